// Round 1
// baseline (751.156 us; speedup 1.0000x reference)
//
#include <hip/hip_runtime.h>
#include <hip/hip_bf16.h>

// ---------------------------------------------------------------------------
// HRAInjectedLinear: out = x @ (W * prod_i (I - 2 u_i u_i^T))^T
// Strategy:
//   u_i = hra_u[:,i]/||.||            (kernel 1)
//   G = U^T U (8x8)                   (kernel 2)
//   Y = W U   [4096,8]                (kernel 3, one 64MB sweep of W)
//   v_i = y_i - 2 sum_{j<i} G_ji v_j  (kernel 4, per-row 8-step recurrence)
//   Wn = W - 2 V U^T  -> bf16         (kernel 5, fused materialize+cast)
//   Xb = bf16(x)                      (kernel 6)
//   out = Xb @ Wn^T  (bf16 MFMA, fp32 accum)   (kernel 7, m97-style)
// ---------------------------------------------------------------------------

#define D_IN   4096
#define D_OUT  4096
#define R_HH   8
#define M_ROWS 8192   // B*S = 4*2048

typedef short bf16x8 __attribute__((ext_vector_type(8)));
typedef float f32x4  __attribute__((ext_vector_type(4)));

__device__ inline unsigned short f2bf(float f) {
    unsigned int x = __float_as_uint(f);
    unsigned int lsb = (x >> 16) & 1u;
    x += 0x7fffu + lsb;                 // round-to-nearest-even
    return (unsigned short)(x >> 16);
}

__device__ inline void async16(const unsigned short* g, short* l) {
    __builtin_amdgcn_global_load_lds(
        (const __attribute__((address_space(1))) void*)g,
        (__attribute__((address_space(3))) void*)l,
        16, 0, 0);
}

// --- kernel 1: column norms of hra_u, write scaled U -----------------------
__global__ void colnorm_scale(const float* __restrict__ hu, float* __restrict__ Us) {
    const int j = blockIdx.x;           // 0..7
    float s = 0.f;
    for (int k = threadIdx.x; k < D_IN; k += 256) {
        float v = hu[k * R_HH + j];
        s += v * v;
    }
    __shared__ float red[256];
    red[threadIdx.x] = s;
    __syncthreads();
    for (int off = 128; off > 0; off >>= 1) {
        if (threadIdx.x < off) red[threadIdx.x] += red[threadIdx.x + off];
        __syncthreads();
    }
    __shared__ float sinv;
    if (threadIdx.x == 0) sinv = 1.0f / sqrtf(red[0]);
    __syncthreads();
    const float inv = sinv;
    for (int k = threadIdx.x; k < D_IN; k += 256)
        Us[k * R_HH + j] = hu[k * R_HH + j] * inv;
}

// --- kernel 2: G = U^T U ----------------------------------------------------
__global__ void gram(const float* __restrict__ Us, float* __restrict__ G) {
    const int i = blockIdx.x >> 3, j = blockIdx.x & 7;
    float s = 0.f;
    for (int k = threadIdx.x; k < D_IN; k += 256)
        s += Us[k * R_HH + i] * Us[k * R_HH + j];
    __shared__ float red[256];
    red[threadIdx.x] = s;
    __syncthreads();
    for (int off = 128; off > 0; off >>= 1) {
        if (threadIdx.x < off) red[threadIdx.x] += red[threadIdx.x + off];
        __syncthreads();
    }
    if (threadIdx.x == 0) G[i * R_HH + j] = red[0];
}

// --- kernel 3: Y = W U  (one block per row of W) ---------------------------
__global__ void wu_gemv(const float* __restrict__ W, const float* __restrict__ Us,
                        float* __restrict__ Y) {
    const int o = blockIdx.x;
    const float* wrow = W + (size_t)o * D_IN;
    float acc[8] = {0,0,0,0,0,0,0,0};
    for (int k = threadIdx.x; k < D_IN; k += 256) {
        float w = wrow[k];
        const float4* u4 = (const float4*)&Us[k * R_HH];
        float4 a = u4[0], b = u4[1];
        acc[0] += w * a.x; acc[1] += w * a.y; acc[2] += w * a.z; acc[3] += w * a.w;
        acc[4] += w * b.x; acc[5] += w * b.y; acc[6] += w * b.z; acc[7] += w * b.w;
    }
    __shared__ float red[8 * 256];
    #pragma unroll
    for (int j = 0; j < 8; j++) red[j * 256 + threadIdx.x] = acc[j];
    __syncthreads();
    for (int off = 128; off > 0; off >>= 1) {
        if (threadIdx.x < off)
            #pragma unroll
            for (int j = 0; j < 8; j++)
                red[j * 256 + threadIdx.x] += red[j * 256 + threadIdx.x + off];
        __syncthreads();
    }
    if (threadIdx.x < 8) Y[(size_t)o * R_HH + threadIdx.x] = red[threadIdx.x * 256];
}

// --- kernel 4: per-row recurrence v_i = y_i - 2 sum_{j<i} G[j][i] v_j ------
__global__ void vcalc(const float* __restrict__ Y, const float* __restrict__ G,
                      float* __restrict__ V) {
    const int o = blockIdx.x * 256 + threadIdx.x;   // 0..4095
    __shared__ float g[64];
    if (threadIdx.x < 64) g[threadIdx.x] = G[threadIdx.x];
    __syncthreads();
    float y[8], v[8];
    const float4* y4 = (const float4*)&Y[(size_t)o * R_HH];
    float4 a = y4[0], b = y4[1];
    y[0]=a.x; y[1]=a.y; y[2]=a.z; y[3]=a.w; y[4]=b.x; y[5]=b.y; y[6]=b.z; y[7]=b.w;
    #pragma unroll
    for (int i = 0; i < 8; i++) {
        float t = y[i];
        #pragma unroll
        for (int j = 0; j < 8; j++)
            if (j < i) t -= 2.0f * g[j * 8 + i] * v[j];
        v[i] = t;
    }
    float4* v4 = (float4*)&V[(size_t)o * R_HH];
    v4[0] = make_float4(v[0], v[1], v[2], v[3]);
    v4[1] = make_float4(v[4], v[5], v[6], v[7]);
}

// --- kernel 5: Wn = bf16(W - 2 V U^T), one block per row -------------------
__global__ void wn_cast(const float* __restrict__ W, const float* __restrict__ Us,
                        const float* __restrict__ V, unsigned short* __restrict__ Wn) {
    const int o = blockIdx.x;
    __shared__ float vs[8];
    if (threadIdx.x < 8) vs[threadIdx.x] = V[(size_t)o * R_HH + threadIdx.x];
    __syncthreads();
    float v[8];
    #pragma unroll
    for (int i = 0; i < 8; i++) v[i] = vs[i];
    const float4* wrow = (const float4*)(W + (size_t)o * D_IN);
    ushort4* wnrow = (ushort4*)(Wn + (size_t)o * D_IN);
    for (int k4 = threadIdx.x; k4 < D_IN / 4; k4 += 256) {
        float4 wv = wrow[k4];
        float wa[4] = {wv.x, wv.y, wv.z, wv.w};
        float out[4];
        #pragma unroll
        for (int e = 0; e < 4; e++) {
            const int k = k4 * 4 + e;
            const float4* u4 = (const float4*)&Us[k * R_HH];
            float4 ua = u4[0], ub = u4[1];
            float corr = v[0]*ua.x + v[1]*ua.y + v[2]*ua.z + v[3]*ua.w
                       + v[4]*ub.x + v[5]*ub.y + v[6]*ub.z + v[7]*ub.w;
            out[e] = wa[e] - 2.0f * corr;
        }
        ushort4 r;
        r.x = f2bf(out[0]); r.y = f2bf(out[1]); r.z = f2bf(out[2]); r.w = f2bf(out[3]);
        wnrow[k4] = r;
    }
}

// --- kernel 6: Xb = bf16(x) -------------------------------------------------
__global__ void cast_x(const float4* __restrict__ x, ushort4* __restrict__ xb, int n4) {
    const int g = blockIdx.x * 256 + threadIdx.x;
    if (g >= n4) return;
    float4 f = x[g];
    ushort4 r;
    r.x = f2bf(f.x); r.y = f2bf(f.y); r.z = f2bf(f.z); r.w = f2bf(f.w);
    xb[g] = r;
}

// --- kernel 7: C = A B^T, bf16 MFMA, m97-style 128x128 tile ----------------
__global__ __launch_bounds__(256) void gemm_bt(
    const unsigned short* __restrict__ A,   // [M][K] bf16 bits
    const unsigned short* __restrict__ B,   // [N][K] bf16 bits
    float* __restrict__ C) {                // [M][N]
    constexpr int K = D_IN, N = D_OUT;
    __shared__ __align__(16) short sA[128 * 32];
    __shared__ __align__(16) short sB[128 * 32];
    const int tid  = threadIdx.x;
    const int lane = tid & 63;
    const int wave = tid >> 6;
    const int wr = (wave >> 1) * 64;
    const int wc = (wave & 1) * 64;
    const size_t bm = (size_t)blockIdx.y * 128;
    const size_t bn = (size_t)blockIdx.x * 128;

    const unsigned short* Ab = A + bm * K;
    const unsigned short* Bb = B + bn * K;
    const int r0 = tid >> 2;               // staging row, pass 0
    const int kc = (tid & 3) * 8;          // staging k-offset
    const size_t ga0 = (size_t)r0 * K + kc;
    const size_t ga1 = (size_t)(r0 + 64) * K + kc;

    f32x4 acc[4][4];
    #pragma unroll
    for (int i = 0; i < 4; i++)
        #pragma unroll
        for (int j = 0; j < 4; j++)
            acc[i][j] = (f32x4){0.f, 0.f, 0.f, 0.f};

    const int arow = wr + (lane & 15);
    const int brow = wc + (lane & 15);
    const int koff = (lane >> 4) * 8;

    for (int k0 = 0; k0 < K; k0 += 32) {
        __syncthreads();                    // LDS free (prev compute done)
        async16(Ab + ga0 + k0, &sA[tid * 8]);
        async16(Ab + ga1 + k0, &sA[2048 + tid * 8]);
        async16(Bb + ga0 + k0, &sB[tid * 8]);
        async16(Bb + ga1 + k0, &sB[2048 + tid * 8]);
        __syncthreads();                    // vmcnt(0)+barrier: tiles ready

        bf16x8 a[4], b[4];
        #pragma unroll
        for (int i = 0; i < 4; i++)
            a[i] = *(const bf16x8*)&sA[(arow + i * 16) * 32 + koff];
        #pragma unroll
        for (int j = 0; j < 4; j++)
            b[j] = *(const bf16x8*)&sB[(brow + j * 16) * 32 + koff];
        #pragma unroll
        for (int i = 0; i < 4; i++)
            #pragma unroll
            for (int j = 0; j < 4; j++)
                acc[i][j] = __builtin_amdgcn_mfma_f32_16x16x32_bf16(
                    a[i], b[j], acc[i][j], 0, 0, 0);
    }

    // epilogue: C/D layout col=lane&15, row=(lane>>4)*4+reg  [m89-verified]
    const int crow0 = (lane >> 4) * 4;
    const int ccol  = lane & 15;
    #pragma unroll
    for (int i = 0; i < 4; i++) {
        #pragma unroll
        for (int j = 0; j < 4; j++) {
            size_t base = (bm + wr + i * 16 + crow0) * (size_t)N
                        + (bn + wc + j * 16 + ccol);
            #pragma unroll
            for (int r = 0; r < 4; r++)
                C[base + (size_t)r * N] = acc[i][j][r];
        }
    }
}

// ---------------------------------------------------------------------------
extern "C" void kernel_launch(void* const* d_in, const int* in_sizes, int n_in,
                              void* d_out, int out_size, void* d_ws, size_t ws_size,
                              hipStream_t stream) {
    const float* x      = (const float*)d_in[0];   // [4,2048,4096]
    const float* weight = (const float*)d_in[1];   // [4096,4096]
    const float* hra_u  = (const float*)d_in[2];   // [4096,8]
    float* out = (float*)d_out;                    // [4,2048,4096]

    // workspace layout (all 16B aligned)
    char* w = (char*)d_ws;
    unsigned short* Xb = (unsigned short*)w;                            // 64 MB
    unsigned short* Wn = (unsigned short*)(w + (size_t)64 * 1024 * 1024);     // 32 MB
    float* Us = (float*)(w + (size_t)96 * 1024 * 1024);                 // 128 KB
    float* Y  = Us + (size_t)D_IN * R_HH;
    float* V  = Y  + (size_t)D_IN * R_HH;
    float* G  = V  + (size_t)D_IN * R_HH;

    colnorm_scale<<<R_HH, 256, 0, stream>>>(hra_u, Us);
    gram<<<R_HH * R_HH, 256, 0, stream>>>(Us, G);
    wu_gemv<<<D_OUT, 256, 0, stream>>>(weight, Us, Y);
    vcalc<<<D_OUT / 256, 256, 0, stream>>>(Y, G, V);
    wn_cast<<<D_OUT, 256, 0, stream>>>(weight, Us, V, Wn);

    const int n4 = M_ROWS * D_IN / 4;
    cast_x<<<(n4 + 255) / 256, 256, 0, stream>>>((const float4*)x, (ushort4*)Xb, n4);

    dim3 grid(D_OUT / 128, M_ROWS / 128);
    gemm_bt<<<grid, 256, 0, stream>>>(Xb, Wn, out);
}